// Round 1
// baseline (43.928 us; speedup 1.0000x reference)
//
#include <hip/hip_runtime.h>
#include <hip/hip_bf16.h>

// Problem constants
constexpr int B = 48, J = 17, H = 128, W = 128, P = 30;
constexpr int HW = H * W;            // 16384
constexpr int NPLANES = B * J;       // 816
constexpr int NJOINTS = B * P * J;   // 24480
// ws layout (floats): [0..815] per-plane masked mse, [816..1631] mask flags, [1632] int64-flag

// ---------------- Kernel 1: per-plane MSE + mask ----------------
__global__ void mse_kernel(const float* __restrict__ outputs,
                           const float* __restrict__ heatmaps,
                           float* __restrict__ ws) {
    int plane = blockIdx.x;          // 0..815
    int b = plane / J, j = plane % J;
    const float4* pred = reinterpret_cast<const float4*>(outputs + ((size_t)b * 2 * J + j) * HW);
    const float4* gt   = reinterpret_cast<const float4*>(heatmaps + (size_t)plane * HW);
    int t = threadIdx.x;             // 0..255

    float sq = 0.f, gs = 0.f;
#pragma unroll
    for (int k = 0; k < 16; ++k) {
        float4 p = pred[t + k * 256];
        float4 g = gt[t + k * 256];
        float d0 = p.x - g.x, d1 = p.y - g.y, d2 = p.z - g.z, d3 = p.w - g.w;
        sq += d0 * d0 + d1 * d1 + d2 * d2 + d3 * d3;
        gs += g.x + g.y + g.z + g.w;
    }
    // wave butterfly then cross-wave via LDS (256 thr = 4 waves)
    for (int off = 32; off > 0; off >>= 1) {
        sq += __shfl_xor(sq, off);
        gs += __shfl_xor(gs, off);
    }
    __shared__ float s_sq[4], s_gs[4];
    int wave = t >> 6;
    if ((t & 63) == 0) { s_sq[wave] = sq; s_gs[wave] = gs; }
    __syncthreads();
    if (t == 0) {
        float tot_sq = s_sq[0] + s_sq[1] + s_sq[2] + s_sq[3];
        float tot_gs = s_gs[0] + s_gs[1] + s_gs[2] + s_gs[3];
        bool mask = tot_gs > 0.f;
        ws[plane]           = mask ? tot_sq * (1.f / HW) : 0.f;
        ws[NPLANES + plane] = mask ? 1.f : 0.f;
    }
}

// ---------------- Kernel 2: finalize hm_loss + dtype probe ----------------
__global__ void finalize_kernel(const float* __restrict__ ws_in,
                                const unsigned* __restrict__ joints_u32,
                                float* __restrict__ ws,
                                float* __restrict__ out) {
    int t = threadIdx.x;             // 256 threads, 1 block
    float s = 0.f, c = 0.f;
    for (int i = t; i < NPLANES; i += 256) {
        s += ws_in[i];
        c += ws_in[NPLANES + i];
    }
    // probe: if joints is int64 (little-endian, values >=0 < 2^31), every odd
    // 32-bit word is 0. If int32 pairs (idx,vis), odd words are vis in {0,1}
    // with ~half == 1.
    unsigned ob = 0;
    for (int i = t; i < NJOINTS; i += 256) ob |= joints_u32[2 * i + 1];
    for (int off = 32; off > 0; off >>= 1) {
        s += __shfl_xor(s, off);
        c += __shfl_xor(c, off);
        ob |= (unsigned)__shfl_xor((int)ob, off);
    }
    __shared__ float s_s[4], s_c[4];
    __shared__ unsigned s_o[4];
    int wave = t >> 6;
    if ((t & 63) == 0) { s_s[wave] = s; s_c[wave] = c; s_o[wave] = ob; }
    __syncthreads();
    if (t == 0) {
        float ts = s_s[0] + s_s[1] + s_s[2] + s_s[3];
        float tc = s_c[0] + s_c[1] + s_c[2] + s_c[3];
        unsigned to = s_o[0] | s_o[1] | s_o[2] | s_o[3];
        out[0] = ts / tc;
        ws[1632] = (to == 0u) ? 1.f : 0.f;   // 1 => int64 layout
    }
}

// ---------------- Kernel 3: AE loss (push, pull) ----------------
__global__ void ae_kernel(const float* __restrict__ outputs,
                          const int* __restrict__ joints32,
                          const long long* __restrict__ joints64,
                          const float* __restrict__ ws,
                          float* __restrict__ out) {
    int b = blockIdx.x;              // 0..47
    int lane = threadIdx.x;          // 0..63 (one wave)
    const float* tags = outputs + ((size_t)b * 2 * J + J) * HW;   // tag planes of batch b
    bool is64 = ws[1632] != 0.f;

    __shared__ float m_sh[P];
    __shared__ int v_sh[P];

    float per_pull = 0.f, m = 0.f;
    int validp = 0;

    if (lane < P) {
        float tv[J];
        int   vv[J];
        int cnt = 0;
        float sum = 0.f;
        if (is64) {
            const long long* jp = joints64 + ((size_t)b * P + lane) * J * 2;
#pragma unroll
            for (int j = 0; j < J; ++j) {
                int idx = (int)jp[2 * j];
                int vis = jp[2 * j + 1] > 0;
                float tval = tags[idx];
                tv[j] = tval; vv[j] = vis;
                cnt += vis;
                sum += vis ? tval : 0.f;
            }
        } else {
            const int* jp = joints32 + ((size_t)b * P + lane) * J * 2;
#pragma unroll
            for (int j = 0; j < J; ++j) {
                int idx = jp[2 * j];
                int vis = jp[2 * j + 1] > 0;
                float tval = tags[idx];
                tv[j] = tval; vv[j] = vis;
                cnt += vis;
                sum += vis ? tval : 0.f;
            }
        }
        float safe = cnt > 0 ? (float)cnt : 1.f;
        m = sum / safe;
        float pp = 0.f;
#pragma unroll
        for (int j = 0; j < J; ++j) {
            float d = tv[j] - m;
            pp += vv[j] ? d * d : 0.f;
        }
        validp = (cnt > 0) ? 1 : 0;
        per_pull = validp ? pp / safe : 0.f;
        m_sh[lane] = m;
        v_sh[lane] = validp;
    }
    __syncthreads();

    // full ordered pairwise sum incl. diagonal (diagonal contributes exactly
    // num_tags, matching reference's "- num_tags")
    float push_p = 0.f;
    if (lane < P && validp) {
#pragma unroll
        for (int k = 0; k < P; ++k) {
            if (v_sh[k]) {
                float d = m - m_sh[k];
                push_p += expf(-d * d);
            }
        }
    }

    float v0 = per_pull, v1 = push_p, v2 = (float)validp;
    for (int off = 32; off > 0; off >>= 1) {
        v0 += __shfl_xor(v0, off);
        v1 += __shfl_xor(v1, off);
        v2 += __shfl_xor(v2, off);
    }
    if (lane == 0) {
        float num_tags = v2;
        float pull = v0 / fmaxf(num_tags, 1.f);
        float push_raw = v1 - num_tags;
        float denom = (num_tags - 1.f) * num_tags;
        float push = (num_tags >= 2.f) ? (push_raw / (denom > 0.f ? denom : 1.f)) * 0.5f : 0.f;
        out[1 + b] = push;           // push: out[1..48]
        out[1 + B + b] = pull;       // pull: out[49..96]
    }
}

extern "C" void kernel_launch(void* const* d_in, const int* in_sizes, int n_in,
                              void* d_out, int out_size, void* d_ws, size_t ws_size,
                              hipStream_t stream) {
    const float* outputs  = (const float*)d_in[0];
    const float* heatmaps = (const float*)d_in[1];
    const void*  joints   = d_in[2];
    float* out = (float*)d_out;
    float* ws  = (float*)d_ws;

    mse_kernel<<<NPLANES, 256, 0, stream>>>(outputs, heatmaps, ws);
    finalize_kernel<<<1, 256, 0, stream>>>(ws, (const unsigned*)joints, ws, out);
    ae_kernel<<<B, 64, 0, stream>>>(outputs, (const int*)joints,
                                    (const long long*)joints, ws, out);
}

// Round 2
// 27.432 us; speedup vs baseline: 1.6013x; 1.6013x over previous
//
#include <hip/hip_runtime.h>
#include <hip/hip_bf16.h>

// Problem constants
constexpr int B = 48, J = 17, H = 128, W = 128, P = 30;
constexpr int HW = H * W;                 // 16384
constexpr int NPLANES = B * J;            // 816
constexpr int CHUNKS_PER_PLANE = 2;       // half-plane = 8192 floats
constexpr int NCHUNK = NPLANES * CHUNKS_PER_PLANE;   // 1632
constexpr int CHUNK_FLOATS = HW / CHUNKS_PER_PLANE;  // 8192
// ws layout: float2 per chunk: ws[2c]=sq_partial, ws[2c+1]=gt_sum_partial

// ---------------- Kernel A: MSE partials (blocks 0..1631) + AE (blocks 1632..1679) ----------------
__global__ __launch_bounds__(256) void fused_kernel(
        const float* __restrict__ outputs,
        const float* __restrict__ heatmaps,
        const unsigned* __restrict__ joints_u32,
        float* __restrict__ ws,
        float* __restrict__ out) {
    int t = threadIdx.x;

    if (blockIdx.x < NCHUNK) {
        // ---- MSE half-plane chunk ----
        int chunk = blockIdx.x;
        int plane = chunk >> 1, half = chunk & 1;
        int b = plane / J, j = plane % J;
        const float4* pred = reinterpret_cast<const float4*>(
            outputs + ((size_t)b * 2 * J + j) * HW + half * CHUNK_FLOATS);
        const float4* gt = reinterpret_cast<const float4*>(
            heatmaps + (size_t)plane * HW + half * CHUNK_FLOATS);

        float sq = 0.f, gs = 0.f;
#pragma unroll
        for (int k = 0; k < CHUNK_FLOATS / 4 / 256; ++k) {   // 8 iters
            float4 p = pred[t + k * 256];
            float4 g = gt[t + k * 256];
            float d0 = p.x - g.x, d1 = p.y - g.y, d2 = p.z - g.z, d3 = p.w - g.w;
            sq += d0 * d0 + d1 * d1 + d2 * d2 + d3 * d3;
            gs += g.x + g.y + g.z + g.w;
        }
        for (int off = 32; off > 0; off >>= 1) {
            sq += __shfl_xor(sq, off);
            gs += __shfl_xor(gs, off);
        }
        __shared__ float s_sq[4], s_gs[4];
        int wave = t >> 6;
        if ((t & 63) == 0) { s_sq[wave] = sq; s_gs[wave] = gs; }
        __syncthreads();
        if (t == 0) {
            ws[2 * chunk]     = s_sq[0] + s_sq[1] + s_sq[2] + s_sq[3];
            ws[2 * chunk + 1] = s_gs[0] + s_gs[1] + s_gs[2] + s_gs[3];
        }
        return;
    }

    // ---- AE for batch b ----
    int b = blockIdx.x - NCHUNK;
    const float* tags = outputs + ((size_t)b * 2 * J + J) * HW;

    // dtype probe on THIS batch's joints region (int64-assumed layout):
    // P*J*2 = 1020 int64 values -> 2040 u32 words; upper halves all zero iff int64.
    const unsigned* jw = joints_u32 + (size_t)b * P * J * 2 * 2;
    unsigned ob = 0;
#pragma unroll
    for (int k = 0; k < 4; ++k) {
        int i = t + k * 256;
        if (i < P * J * 2) ob |= jw[2 * i + 1];
    }
    __shared__ unsigned s_ob[4];
    for (int off = 32; off > 0; off >>= 1) ob |= (unsigned)__shfl_xor((int)ob, off);
    int wv = t >> 6;
    if ((t & 63) == 0) s_ob[wv] = ob;
    __shared__ float m_sh[P];
    __shared__ int v_sh[P];
    __syncthreads();
    bool is64 = (s_ob[0] | s_ob[1] | s_ob[2] | s_ob[3]) == 0u;

    if (t >= 64) return;
    int lane = t;

    float per_pull = 0.f, m = 0.f;
    int validp = 0;

    if (lane < P) {
        float tv[J];
        int   vv[J];
        int cnt = 0;
        float sum = 0.f;
        if (is64) {
            const long long* jp = reinterpret_cast<const long long*>(joints_u32)
                                  + ((size_t)b * P + lane) * J * 2;
#pragma unroll
            for (int j = 0; j < J; ++j) {
                int idx = (int)jp[2 * j];
                int vis = jp[2 * j + 1] > 0;
                float tval = tags[idx];
                tv[j] = tval; vv[j] = vis;
                cnt += vis;
                sum += vis ? tval : 0.f;
            }
        } else {
            const int* jp = reinterpret_cast<const int*>(joints_u32)
                            + ((size_t)b * P + lane) * J * 2;
#pragma unroll
            for (int j = 0; j < J; ++j) {
                int idx = jp[2 * j];
                int vis = jp[2 * j + 1] > 0;
                float tval = tags[idx];
                tv[j] = tval; vv[j] = vis;
                cnt += vis;
                sum += vis ? tval : 0.f;
            }
        }
        float safe = cnt > 0 ? (float)cnt : 1.f;
        m = sum / safe;
        float pp = 0.f;
#pragma unroll
        for (int j = 0; j < J; ++j) {
            float d = tv[j] - m;
            pp += vv[j] ? d * d : 0.f;
        }
        validp = (cnt > 0) ? 1 : 0;
        per_pull = validp ? pp / safe : 0.f;
        m_sh[lane] = m;
        v_sh[lane] = validp;
    }
    // single wave: no barrier needed beyond the earlier __syncthreads? m_sh/v_sh
    // written and read within one wave -> lock-step, but be safe with wave-wide
    // ordering (writes then reads by other lanes). s_waitcnt handles LDS; a
    // __syncthreads here would hang (other waves exited) -- use builtin wave sync:
    __builtin_amdgcn_s_waitcnt(0);   // drain lgkm for this wave

    float push_p = 0.f;
    if (lane < P && validp) {
#pragma unroll
        for (int k = 0; k < P; ++k) {
            if (v_sh[k]) {
                float d = m - m_sh[k];
                push_p += __expf(-d * d);
            }
        }
    }

    float v0 = per_pull, v1 = push_p, v2 = (float)validp;
    for (int off = 32; off > 0; off >>= 1) {
        v0 += __shfl_xor(v0, off);
        v1 += __shfl_xor(v1, off);
        v2 += __shfl_xor(v2, off);
    }
    if (lane == 0) {
        float num_tags = v2;
        float pull = v0 / fmaxf(num_tags, 1.f);
        float push_raw = v1 - num_tags;
        float denom = (num_tags - 1.f) * num_tags;
        float push = (num_tags >= 2.f) ? (push_raw / (denom > 0.f ? denom : 1.f)) * 0.5f : 0.f;
        out[1 + b] = push;
        out[1 + B + b] = pull;
    }
}

// ---------------- Kernel B: fold MSE partials -> out[0] ----------------
__global__ __launch_bounds__(256) void finalize_kernel(const float* __restrict__ ws,
                                                       float* __restrict__ out) {
    int t = threadIdx.x;
    float s = 0.f, c = 0.f;
    for (int p = t; p < NPLANES; p += 256) {
        int c0 = 2 * p, c1 = 2 * p + 1;
        float sq = ws[2 * c0] + ws[2 * c1];
        float gs = ws[2 * c0 + 1] + ws[2 * c1 + 1];
        bool mask = gs > 0.f;
        s += mask ? sq * (1.f / HW) : 0.f;
        c += mask ? 1.f : 0.f;
    }
    for (int off = 32; off > 0; off >>= 1) {
        s += __shfl_xor(s, off);
        c += __shfl_xor(c, off);
    }
    __shared__ float s_s[4], s_c[4];
    int wave = t >> 6;
    if ((t & 63) == 0) { s_s[wave] = s; s_c[wave] = c; }
    __syncthreads();
    if (t == 0) {
        out[0] = (s_s[0] + s_s[1] + s_s[2] + s_s[3]) /
                 (s_c[0] + s_c[1] + s_c[2] + s_c[3]);
    }
}

extern "C" void kernel_launch(void* const* d_in, const int* in_sizes, int n_in,
                              void* d_out, int out_size, void* d_ws, size_t ws_size,
                              hipStream_t stream) {
    const float* outputs  = (const float*)d_in[0];
    const float* heatmaps = (const float*)d_in[1];
    const unsigned* joints = (const unsigned*)d_in[2];
    float* out = (float*)d_out;
    float* ws  = (float*)d_ws;

    fused_kernel<<<NCHUNK + B, 256, 0, stream>>>(outputs, heatmaps, joints, ws, out);
    finalize_kernel<<<1, 256, 0, stream>>>(ws, out);
}